// Round 2
// baseline (759.950 us; speedup 1.0000x reference)
//
#include <hip/hip_runtime.h>
#include <stdint.h>

// GATConv fused v12 = v11 restructured for 2x occupancy (the R1 counters show
// a latency-bound kernel: no pipe >27%, occupancy 21.6% = 8 waves/CU pinned by
// 148KB LDS -> 1 block/CU, grid == CU count).
//   One 1024-thread block per CU (16 waves) instead of 512. Each wave's work
//   halves along a col/n axis; per-CU LDS traffic, MFMA count, swizzles, and
//   dbuf prefetch are IDENTICAL to v11 -- only concurrency doubles:
//     QK:  wave (rg=w>>1, ch=w&1) does 16 rows x 32 cols (accS[2], 16 K-reads)
//     max: per-wave partial over 32 cols; 1KB LDS exchange + barrier combines
//          the (ch=0, ch=1) pair; both waves compute bit-identical mrow.
//     PV:  wave does 16 rows x 128 n (accO 8 f32x4 = 32 VGPRs), reading the
//          row-group's full 64-k P strip (incl. partner half) after a barrier.
//   3 barriers/tile (pmax, P-ready, dbuf) vs 1. VGPR nominal drops ~40 ->
//   launch_bounds(1024,4) caps at 128 for 4 waves/SIMD.

typedef _Float16 f16;
typedef unsigned short u16;
typedef __attribute__((ext_vector_type(8))) _Float16 f16x8;
typedef __attribute__((ext_vector_type(4))) _Float16 f16x4;
typedef __attribute__((ext_vector_type(4))) float f32x4;

#define NN 8192
#define DD 256
#define BR 128
#define BC 64
#define CCH 4
#define COLS (NN / CCH)  // 2048
#define NIT (COLS / BC)  // 32
#define PSTR 80          // P row stride in f16

#define MFMA(a, b, c) __builtin_amdgcn_mfma_f32_16x16x32_f16((a), (b), (c), 0, 0, 0)

__device__ __forceinline__ void gl2lds16(const void* g, void* l) {
    __builtin_amdgcn_global_load_lds(
        (const __attribute__((address_space(1))) unsigned int*)g,
        (__attribute__((address_space(3))) unsigned int*)l, 16, 0, 0);
}

__device__ __forceinline__ u16 f16bits(f16 h) {
    union { f16 h; u16 u; } c;
    c.h = h;
    return c.u;
}

// ---------------- split X to fp16 hi/lo (4 elems/thread) ----------------
__global__ void splitX_kernel(const float4* __restrict__ X, f16x4* __restrict__ Xh,
                              f16x4* __restrict__ Xl) {
    const int i = blockIdx.x * blockDim.x + threadIdx.x;  // 524288
    const float4 v = X[i];
    const f16 h0 = (f16)v.x, h1 = (f16)v.y, h2 = (f16)v.z, h3 = (f16)v.w;
    f16x4 H = {h0, h1, h2, h3};
    f16x4 L = {(f16)(v.x - (float)h0), (f16)(v.y - (float)h1), (f16)(v.z - (float)h2),
               (f16)(v.w - (float)h3)};
    Xh[i] = H;
    Xl[i] = L;
}

// W[k][n] (3 mats 256x256) -> Wt[(mat*256+n)][k] fp16 hi/lo (transposed)
__global__ void splitW_kernel(const float* __restrict__ Wq, const float* __restrict__ Wk,
                              const float* __restrict__ Wv, f16* __restrict__ WtH,
                              f16* __restrict__ WtL) {
    const int i = blockIdx.x * blockDim.x + threadIdx.x;  // 3*65536
    const int mat = i >> 16;
    const int k = (i >> 8) & 255;
    const int n = i & 255;
    const float* W = (mat == 0) ? Wq : ((mat == 1) ? Wk : Wv);
    const float v = W[k * 256 + n];
    const f16 h = (f16)v;
    const size_t o = (size_t)(mat * 256 + n) * 256 + k;
    WtH[o] = h;
    WtL[o] = (f16)(v - (float)h);
}

// ---------------- QKV GEMM: LDS-staged W chunks, X frags in registers ----------------
__global__ __launch_bounds__(256, 2) void qkv_kernel(
    const f16* __restrict__ Xh, const f16* __restrict__ Xl,
    const f16* __restrict__ WtH, const f16* __restrict__ WtL,
    f16* __restrict__ Qh, f16* __restrict__ Ql,
    f16* __restrict__ Kh, f16* __restrict__ Vt) {
    __shared__ f16 Wh[64 * 256];
    __shared__ f16 Wl[64 * 256];
    const int lane = threadIdx.x & 63;
    const int w = threadIdx.x >> 6;
    const int l15 = lane & 15;
    const int quad = lane >> 4;
    const int r0 = blockIdx.x * 64;
    const int mat = blockIdx.y;

    f16x8 xh[8], xl[8];
    const size_t xb = (size_t)(r0 + w * 16 + l15) * DD + quad * 8;
#pragma unroll
    for (int kc = 0; kc < 8; ++kc) {
        xh[kc] = *(const f16x8*)(Xh + xb + kc * 32);
        xl[kc] = *(const f16x8*)(Xl + xb + kc * 32);
    }
    const int orow = r0 + w * 16 + quad * 4;

#pragma unroll 1
    for (int c = 0; c < 4; ++c) {
        const int nb = mat * 256 + c * 64;
#pragma unroll
        for (int i = 0; i < 8; ++i) {
            const int r = w * 16 + i * 2 + (lane >> 5);
            gl2lds16(WtH + (size_t)(nb + r) * DD + (((lane & 31) ^ (r & 7)) * 8),
                     &Wh[(w * 16 + i * 2) * 256]);
        }
#pragma unroll
        for (int i = 0; i < 8; ++i) {
            const int r = w * 16 + i * 2 + (lane >> 5);
            gl2lds16(WtL + (size_t)(nb + r) * DD + (((lane & 31) ^ (r & 7)) * 8),
                     &Wl[(w * 16 + i * 2) * 256]);
        }
        __syncthreads();

        const f32x4 fzero = {0.f, 0.f, 0.f, 0.f};
        f32x4 acc[4];
#pragma unroll
        for (int nt = 0; nt < 4; ++nt) acc[nt] = fzero;
#pragma unroll
        for (int kc = 0; kc < 8; ++kc)
#pragma unroll
            for (int nt = 0; nt < 4; ++nt) {
                const int r = nt * 16 + l15;
                const int blk = (((kc * 4 + quad) ^ (r & 7)) * 8);
                const f16x8 wh = *(const f16x8*)&Wh[r * 256 + blk];
                const f16x8 wl = *(const f16x8*)&Wl[r * 256 + blk];
                acc[nt] = MFMA(xh[kc], wh, acc[nt]);
                acc[nt] = MFMA(xh[kc], wl, acc[nt]);
                acc[nt] = MFMA(xl[kc], wh, acc[nt]);
            }

        if (mat == 0) {
#pragma unroll
            for (int nt = 0; nt < 4; ++nt)
#pragma unroll
                for (int rg = 0; rg < 4; ++rg) {
                    const int col = c * 64 + nt * 16 + l15;
                    const float v = acc[nt][rg];
                    const f16 h = (f16)v;
                    Qh[(size_t)(orow + rg) * DD + col] = h;
                    Ql[(size_t)(orow + rg) * DD + col] = (f16)(v - (float)h);
                }
        } else if (mat == 1) {
#pragma unroll
            for (int nt = 0; nt < 4; ++nt)
#pragma unroll
                for (int rg = 0; rg < 4; ++rg) {
                    const int col = c * 64 + nt * 16 + l15;
                    Kh[(size_t)(orow + rg) * DD + col] = (f16)acc[nt][rg];
                }
        } else {
#pragma unroll
            for (int nt = 0; nt < 4; ++nt) {
                const int n = c * 64 + nt * 16 + l15;
                ushort4 pk;
                pk.x = f16bits((f16)acc[nt][0]);
                pk.y = f16bits((f16)acc[nt][1]);
                pk.z = f16bits((f16)acc[nt][2]);
                pk.w = f16bits((f16)acc[nt][3]);
                *(ushort4*)(Vt + (size_t)n * NN + orow) = pk;
            }
        }
        __syncthreads();
    }
}

// ---------------- flash kernel v12: 16 waves/block, col/n split wave pairs --------
// grid 256 linear (1 block/CU): cch = bid&3, rowblk = bid>>2, BR=128.
__global__ __launch_bounds__(1024, 4) void flash_kernel(
    const f16* __restrict__ Qh, const f16* __restrict__ Ql,
    const f16* __restrict__ Kh, const f16* __restrict__ Vt,
    const int* __restrict__ A,
    float* __restrict__ pO, float* __restrict__ pM, float* __restrict__ pL) {
    __shared__ f16 Klds[2][64 * 256];   // 64 KB dbuf, [j][k] XOR-swizzled by j&7
    __shared__ f16 Vlds[2][256 * 64];   // 64 KB dbuf, [n][j] swizzled by n&7
    __shared__ f16 Plds[8][16 * PSTR];  // 20 KB, per ROW-GROUP, stride 80 + row-XOR
    __shared__ float pmaxLds[8][2][16]; // 1 KB, pair max exchange (reused for l-sum)

    const int lane = threadIdx.x & 63;
    const int w = threadIdx.x >> 6;  // 0..15
    const int rg = w >> 1;           // row group 0..7 (16 rows each)
    const int ch = w & 1;            // col half (QK: 32 cols; PV: 128 n)
    const int l15 = lane & 15;
    const int quad = lane >> 4;
    const int bid = blockIdx.x;
    const int cch = bid & 3;
    const int r0 = (bid >> 2) * BR;
    const int col0 = cch * COLS;

    // Q fragments resident (A-layout m=l15, k=quad*8+i), hi+lo
    f16x8 qh[8], ql[8];
    {
        const size_t qb = (size_t)(r0 + rg * 16 + l15) * DD + quad * 8;
#pragma unroll
        for (int kc = 0; kc < 8; ++kc) {
            qh[kc] = *(const f16x8*)(Qh + qb + kc * 32);
            ql[kc] = *(const f16x8*)(Ql + qb + kc * 32);
        }
    }

    const f32x4 fzero = {0.f, 0.f, 0.f, 0.f};
    f32x4 accO[8];  // 16 rows x 128 n (ch half)
#pragma unroll
    for (int i = 0; i < 8; ++i) accO[i] = fzero;
    float mrow[4], lpart[4];  // mrow identical across the ch pair by construction
#pragma unroll
    for (int r = 0; r < 4; ++r) {
        mrow[r] = -1e30f;
        lpart[r] = 0.f;
    }
    const int growb = r0 + rg * 16 + quad * 4;
    f16* Pw = &Plds[rg][0];

    // stage tile `t` into buffer `b` (each of 16 waves: 2 K-instrs + 2 V-instrs)
    auto stage = [&](int t, int b) {
        const int j0s = col0 + t * BC;
#pragma unroll
        for (int i = 0; i < 2; ++i) {
            const int r = w * 4 + i * 2 + (lane >> 5);
            gl2lds16(Kh + (size_t)(j0s + r) * DD + (((lane & 31) ^ (r & 7)) * 8),
                     &Klds[b][(w * 4 + i * 2) * 256]);
        }
#pragma unroll
        for (int i = 0; i < 2; ++i) {
            const int n = w * 16 + i * 8 + (lane >> 3);
            gl2lds16(Vt + (size_t)n * NN + j0s + (((lane & 7) ^ (n & 7)) * 8),
                     &Vlds[b][(w * 16 + i * 8) * 64]);
        }
    };

    // prologue: stage tile 0 -> buf 0
    stage(0, 0);
    __syncthreads();

#pragma unroll 1
    for (int it = 0; it < NIT; ++it) {
        const int cur = it & 1;
        const int j0 = col0 + it * BC;

        // stage NEXT tile into alternate buffer (drained at the pmax barrier;
        // still covered by the QK phase)
        if (it + 1 < NIT) stage(it + 1, cur ^ 1);

        // adjacency for this wave's 32-col half (nontemporal: streamed once)
        int av[4][2];
#pragma unroll
        for (int rgi = 0; rgi < 4; ++rgi)
#pragma unroll
            for (int jt = 0; jt < 2; ++jt)
                av[rgi][jt] = __builtin_nontemporal_load(
                    A + (size_t)(growb + rgi) * NN + j0 + ch * 32 + jt * 16 + l15);

        // S = (Qh+Ql)·Kh^T : 16 rows x 32 cols per wave
        f32x4 accS[2];
        accS[0] = fzero;
        accS[1] = fzero;
        __builtin_amdgcn_s_setprio(1);
#pragma unroll
        for (int kc = 0; kc < 8; ++kc)
#pragma unroll
            for (int jt = 0; jt < 2; ++jt) {
                const int r = ch * 32 + jt * 16 + l15;
                const f16x8 kf =
                    *(const f16x8*)&Klds[cur][r * 256 + (((kc * 4 + quad) ^ (r & 7)) * 8)];
                accS[jt] = MFMA(qh[kc], kf, accS[jt]);
                accS[jt] = MFMA(ql[kc], kf, accS[jt]);
            }
        __builtin_amdgcn_s_setprio(0);

        // phase 1: mask + per-wave partial row max (over this 32-col half)
        float mymx[4];
#pragma unroll
        for (int rgi = 0; rgi < 4; ++rgi) {
            const int gr = growb + rgi;
            float mx = -3.0e38f;
#pragma unroll
            for (int jt = 0; jt < 2; ++jt) {
                const int gc = j0 + ch * 32 + jt * 16 + l15;
                const float s = (av[rgi][jt] != 0 || gr == gc) ? accS[jt][rgi] : -3.0e38f;
                accS[jt][rgi] = s;
                mx = fmaxf(mx, s);
            }
#pragma unroll
            for (int off = 1; off < 16; off <<= 1) mx = fmaxf(mx, __shfl_xor(mx, off, 64));
            mymx[rgi] = mx;
            if (l15 == 0) pmaxLds[rg][ch][quad * 4 + rgi] = mx;
        }
        __syncthreads();  // pmax exchange (also drains stage loads)

        // phase 2: full row max, exact defer-rescale, exp, P write.
        // Both waves of the pair compute identical mrow -> consistent state.
#pragma unroll
        for (int rgi = 0; rgi < 4; ++rgi) {
            const float other = pmaxLds[rg][ch ^ 1][quad * 4 + rgi];
            const float mxf = fmaxf(mymx[rgi], other);
            const float mnew = fmaxf(mrow[rgi], mxf);
            if (__any(mnew > mrow[rgi])) {
                const float al = __expf(mrow[rgi] - mnew);
                mrow[rgi] = mnew;
                lpart[rgi] *= al;
#pragma unroll
                for (int nt = 0; nt < 8; ++nt) accO[nt][rgi] *= al;
            }
            float rs = 0.f;
            const int row = quad * 4 + rgi;
#pragma unroll
            for (int jt = 0; jt < 2; ++jt) {
                const float s = accS[jt][rgi];
                const float e = (s > -1.0e37f) ? __expf(s - mrow[rgi]) : 0.f;
                rs += e;
                Pw[row * PSTR + ((ch * 32 + jt * 16 + l15) ^ ((row & 7) << 3))] = (f16)e;
            }
            lpart[rgi] += rs;  // per-lane partial over own half; epilogue combines
        }
        __syncthreads();  // P (both halves) visible

        // PV: 16 rows x 128 n per wave, full 64-k P strip of this row group
        f16x8 pf[2];
        pf[0] = *(const f16x8*)&Pw[l15 * PSTR + ((quad * 8) ^ ((l15 & 7) << 3))];
        pf[1] = *(const f16x8*)&Pw[l15 * PSTR + ((32 + quad * 8) ^ ((l15 & 7) << 3))];
        __builtin_amdgcn_s_setprio(1);
#pragma unroll
        for (int nt = 0; nt < 8; ++nt)
#pragma unroll
            for (int kc2 = 0; kc2 < 2; ++kc2) {
                const int n = ch * 128 + nt * 16 + l15;
                const f16x8 vf =
                    *(const f16x8*)&Vlds[cur][n * 64 + (((kc2 * 4 + quad) ^ (n & 7)) * 8)];
                accO[nt] = MFMA(pf[kc2], vf, accO[nt]);
            }
        __builtin_amdgcn_s_setprio(0);

        // end barrier: compute(it) done before dbuf overwrite next iter
        __syncthreads();
    }

    // epilogue: reduce per-lane l partials across 16 lanes
#pragma unroll
    for (int rgi = 0; rgi < 4; ++rgi)
#pragma unroll
        for (int off = 1; off < 16; off <<= 1)
            lpart[rgi] += __shfl_xor(lpart[rgi], off, 64);

    // combine l across the ch pair via LDS (pmaxLds reused; loop fully barriered)
    if (l15 == 0)
#pragma unroll
        for (int rgi = 0; rgi < 4; ++rgi) pmaxLds[rg][ch][quad * 4 + rgi] = lpart[rgi];
    __syncthreads();

    // write partials
#pragma unroll
    for (int nt = 0; nt < 8; ++nt)
#pragma unroll
        for (int rgi = 0; rgi < 4; ++rgi)
            pO[((size_t)cch * NN + growb + rgi) * DD + ch * 128 + nt * 16 + l15] =
                accO[nt][rgi];
    if (ch == 0 && l15 == 0) {
#pragma unroll
        for (int rgi = 0; rgi < 4; ++rgi) {
            pM[(size_t)cch * NN + growb + rgi] = mrow[rgi];
            pL[(size_t)cch * NN + growb + rgi] =
                pmaxLds[rg][0][quad * 4 + rgi] + pmaxLds[rg][1][quad * 4 + rgi];
        }
    }
}

// ---------------- merge partials (8 rows/block) ----------------
__global__ __launch_bounds__(256) void merge_kernel(const float* __restrict__ pO,
                                                    const float* __restrict__ pM,
                                                    const float* __restrict__ pL,
                                                    float* __restrict__ out) {
    const int n = threadIdx.x;
#pragma unroll 1
    for (int rr = 0; rr < 8; ++rr) {
        const int row = blockIdx.x * 8 + rr;
        float mc[CCH], lc[CCH];
        float M = -3e38f;
#pragma unroll
        for (int c = 0; c < CCH; ++c) {
            mc[c] = pM[(size_t)c * NN + row];
            lc[c] = pL[(size_t)c * NN + row];
            M = fmaxf(M, mc[c]);
        }
        float L = 0.f, acc = 0.f;
#pragma unroll
        for (int c = 0; c < CCH; ++c) {
            const float wgt = __expf(mc[c] - M);
            L += wgt * lc[c];
            acc += wgt * pO[((size_t)c * NN + row) * DD + n];
        }
        out[(size_t)row * DD + n] = acc / L;
    }
}

extern "C" void kernel_launch(void* const* d_in, const int* in_sizes, int n_in,
                              void* d_out, int out_size, void* d_ws, size_t ws_size,
                              hipStream_t stream) {
    const float* X = (const float*)d_in[0];
    const int* A = (const int*)d_in[1];
    const float* Wq = (const float*)d_in[2];
    const float* Wk = (const float*)d_in[3];
    const float* Wv = (const float*)d_in[4];
    float* out = (float*)d_out;

    char* ws = (char*)d_ws;
    const size_t MB = 1ull << 20;
    f16* Xh = (f16*)(ws + 0 * MB);
    f16* Xl = (f16*)(ws + 4 * MB);
    f16* WtH = (f16*)(ws + 8 * MB);
    f16* WtL = (f16*)(ws + 8 * MB + 512 * 1024);
    f16* Qh = (f16*)(ws + 9 * MB);
    f16* Ql = (f16*)(ws + 13 * MB);
    f16* Kh = (f16*)(ws + 17 * MB);
    f16* Vt = (f16*)(ws + 21 * MB);
    float* pO = (float*)(ws + 25 * MB);
    float* pM = (float*)(ws + 57 * MB);
    float* pL = (float*)(ws + 57 * MB + 256 * 1024);
    (void)ws_size; (void)in_sizes; (void)n_in; (void)out_size;

    splitX_kernel<<<2048, 256, 0, stream>>>((const float4*)X, (f16x4*)Xh, (f16x4*)Xl);
    splitW_kernel<<<768, 256, 0, stream>>>(Wq, Wk, Wv, WtH, WtL);
    qkv_kernel<<<dim3(NN / 64, 3), 256, 0, stream>>>(Xh, Xl, WtH, WtL, Qh, Ql, Kh, Vt);
    flash_kernel<<<(NN / BR) * CCH, 1024, 0, stream>>>(Qh, Ql, Kh, Vt, A, pO, pM, pL);
    merge_kernel<<<NN / 8, 256, 0, stream>>>(pO, pM, pL, out);
}

// Round 3
// 517.078 us; speedup vs baseline: 1.4697x; 1.4697x over previous
//
#include <hip/hip_runtime.h>
#include <stdint.h>

// GATConv fused v13 = v11 (proven 183us flash) + intra-wave phase overlap.
// R2's v12 (1024-thr, launch_bounds(1024,4)) spilled: unified VGPR/AGPR file
// split 64/64, ~40 regs short -> FETCH exploded 156->928MB. Reverted.
// R1 counters showed phase-locked latency-bound execution (MfmaUtil 24 +
// VALUBusy 26, LDS ~50% by arithmetic, nothing saturated): all 8 waves do
// QK / softmax / PV in lockstep between barriers.
// v13: split the 64-col tile into TWO online-softmax sub-tiles (h0/h1):
//   QK(h0); QK(h1); SM(h0); PV(h0); SM(h1); PV(h1)
// Two independent dep chains/wave -> SM(h0) VALU overlaps QK(h1) MFMA drain,
// SM(h1) overlaps PV(h0). Exact online softmax (extra rescale is defer-skipped
// when the running max doesn't grow). Same regs, same LDS, same barriers.

typedef _Float16 f16;
typedef unsigned short u16;
typedef __attribute__((ext_vector_type(8))) _Float16 f16x8;
typedef __attribute__((ext_vector_type(4))) _Float16 f16x4;
typedef __attribute__((ext_vector_type(4))) float f32x4;

#define NN 8192
#define DD 256
#define BR 128
#define BC 64
#define CCH 4
#define COLS (NN / CCH)  // 2048
#define NIT (COLS / BC)  // 32
#define PSTR 80          // P row stride in f16

#define MFMA(a, b, c) __builtin_amdgcn_mfma_f32_16x16x32_f16((a), (b), (c), 0, 0, 0)

__device__ __forceinline__ void gl2lds16(const void* g, void* l) {
    __builtin_amdgcn_global_load_lds(
        (const __attribute__((address_space(1))) unsigned int*)g,
        (__attribute__((address_space(3))) unsigned int*)l, 16, 0, 0);
}

__device__ __forceinline__ u16 f16bits(f16 h) {
    union { f16 h; u16 u; } c;
    c.h = h;
    return c.u;
}

// ---------------- split X to fp16 hi/lo (4 elems/thread) ----------------
__global__ void splitX_kernel(const float4* __restrict__ X, f16x4* __restrict__ Xh,
                              f16x4* __restrict__ Xl) {
    const int i = blockIdx.x * blockDim.x + threadIdx.x;  // 524288
    const float4 v = X[i];
    const f16 h0 = (f16)v.x, h1 = (f16)v.y, h2 = (f16)v.z, h3 = (f16)v.w;
    f16x4 H = {h0, h1, h2, h3};
    f16x4 L = {(f16)(v.x - (float)h0), (f16)(v.y - (float)h1), (f16)(v.z - (float)h2),
               (f16)(v.w - (float)h3)};
    Xh[i] = H;
    Xl[i] = L;
}

// W[k][n] (3 mats 256x256) -> Wt[(mat*256+n)][k] fp16 hi/lo (transposed)
__global__ void splitW_kernel(const float* __restrict__ Wq, const float* __restrict__ Wk,
                              const float* __restrict__ Wv, f16* __restrict__ WtH,
                              f16* __restrict__ WtL) {
    const int i = blockIdx.x * blockDim.x + threadIdx.x;  // 3*65536
    const int mat = i >> 16;
    const int k = (i >> 8) & 255;
    const int n = i & 255;
    const float* W = (mat == 0) ? Wq : ((mat == 1) ? Wk : Wv);
    const float v = W[k * 256 + n];
    const f16 h = (f16)v;
    const size_t o = (size_t)(mat * 256 + n) * 256 + k;
    WtH[o] = h;
    WtL[o] = (f16)(v - (float)h);
}

// ---------------- QKV GEMM: LDS-staged W chunks, X frags in registers ----------------
__global__ __launch_bounds__(256, 2) void qkv_kernel(
    const f16* __restrict__ Xh, const f16* __restrict__ Xl,
    const f16* __restrict__ WtH, const f16* __restrict__ WtL,
    f16* __restrict__ Qh, f16* __restrict__ Ql,
    f16* __restrict__ Kh, f16* __restrict__ Vt) {
    __shared__ f16 Wh[64 * 256];
    __shared__ f16 Wl[64 * 256];
    const int lane = threadIdx.x & 63;
    const int w = threadIdx.x >> 6;
    const int l15 = lane & 15;
    const int quad = lane >> 4;
    const int r0 = blockIdx.x * 64;
    const int mat = blockIdx.y;

    f16x8 xh[8], xl[8];
    const size_t xb = (size_t)(r0 + w * 16 + l15) * DD + quad * 8;
#pragma unroll
    for (int kc = 0; kc < 8; ++kc) {
        xh[kc] = *(const f16x8*)(Xh + xb + kc * 32);
        xl[kc] = *(const f16x8*)(Xl + xb + kc * 32);
    }
    const int orow = r0 + w * 16 + quad * 4;

#pragma unroll 1
    for (int c = 0; c < 4; ++c) {
        const int nb = mat * 256 + c * 64;
#pragma unroll
        for (int i = 0; i < 8; ++i) {
            const int r = w * 16 + i * 2 + (lane >> 5);
            gl2lds16(WtH + (size_t)(nb + r) * DD + (((lane & 31) ^ (r & 7)) * 8),
                     &Wh[(w * 16 + i * 2) * 256]);
        }
#pragma unroll
        for (int i = 0; i < 8; ++i) {
            const int r = w * 16 + i * 2 + (lane >> 5);
            gl2lds16(WtL + (size_t)(nb + r) * DD + (((lane & 31) ^ (r & 7)) * 8),
                     &Wl[(w * 16 + i * 2) * 256]);
        }
        __syncthreads();

        const f32x4 fzero = {0.f, 0.f, 0.f, 0.f};
        f32x4 acc[4];
#pragma unroll
        for (int nt = 0; nt < 4; ++nt) acc[nt] = fzero;
#pragma unroll
        for (int kc = 0; kc < 8; ++kc)
#pragma unroll
            for (int nt = 0; nt < 4; ++nt) {
                const int r = nt * 16 + l15;
                const int blk = (((kc * 4 + quad) ^ (r & 7)) * 8);
                const f16x8 wh = *(const f16x8*)&Wh[r * 256 + blk];
                const f16x8 wl = *(const f16x8*)&Wl[r * 256 + blk];
                acc[nt] = MFMA(xh[kc], wh, acc[nt]);
                acc[nt] = MFMA(xh[kc], wl, acc[nt]);
                acc[nt] = MFMA(xl[kc], wh, acc[nt]);
            }

        if (mat == 0) {
#pragma unroll
            for (int nt = 0; nt < 4; ++nt)
#pragma unroll
                for (int rg = 0; rg < 4; ++rg) {
                    const int col = c * 64 + nt * 16 + l15;
                    const float v = acc[nt][rg];
                    const f16 h = (f16)v;
                    Qh[(size_t)(orow + rg) * DD + col] = h;
                    Ql[(size_t)(orow + rg) * DD + col] = (f16)(v - (float)h);
                }
        } else if (mat == 1) {
#pragma unroll
            for (int nt = 0; nt < 4; ++nt)
#pragma unroll
                for (int rg = 0; rg < 4; ++rg) {
                    const int col = c * 64 + nt * 16 + l15;
                    Kh[(size_t)(orow + rg) * DD + col] = (f16)acc[nt][rg];
                }
        } else {
#pragma unroll
            for (int nt = 0; nt < 4; ++nt) {
                const int n = c * 64 + nt * 16 + l15;
                ushort4 pk;
                pk.x = f16bits((f16)acc[nt][0]);
                pk.y = f16bits((f16)acc[nt][1]);
                pk.z = f16bits((f16)acc[nt][2]);
                pk.w = f16bits((f16)acc[nt][3]);
                *(ushort4*)(Vt + (size_t)n * NN + orow) = pk;
            }
        }
        __syncthreads();
    }
}

// ---------------- flash kernel v13 (v11 + h0/h1 sub-tile pipeline) ----------------
// grid 256 linear: cch = bid&3 (pins chunk to XCD pair), rowblk = bid>>2, BR=128.
__global__ __launch_bounds__(512, 2) void flash_kernel(
    const f16* __restrict__ Qh, const f16* __restrict__ Ql,
    const f16* __restrict__ Kh, const f16* __restrict__ Vt,
    const int* __restrict__ A,
    float* __restrict__ pO, float* __restrict__ pM, float* __restrict__ pL) {
    __shared__ f16 Klds[2][64 * 256];   // 64 KB dbuf, [j][k] XOR-swizzled by j&7
    __shared__ f16 Vlds[2][256 * 64];   // 64 KB dbuf, [n][j] swizzled by n&7
    __shared__ f16 Plds[8][16 * PSTR];  // 20 KB, per-wave, stride 80 + row-XOR

    const int lane = threadIdx.x & 63;
    const int w = threadIdx.x >> 6;  // 0..7
    const int l15 = lane & 15;
    const int quad = lane >> 4;
    const int bid = blockIdx.x;
    const int cch = bid & 3;
    const int r0 = (bid >> 2) * BR;
    const int col0 = cch * COLS;

    // Q fragments resident (A-layout m=l15, k=quad*8+i), hi+lo
    f16x8 qh[8], ql[8];
    {
        const size_t qb = (size_t)(r0 + w * 16 + l15) * DD + quad * 8;
#pragma unroll
        for (int kc = 0; kc < 8; ++kc) {
            qh[kc] = *(const f16x8*)(Qh + qb + kc * 32);
            ql[kc] = *(const f16x8*)(Ql + qb + kc * 32);
        }
    }

    const f32x4 fzero = {0.f, 0.f, 0.f, 0.f};
    f32x4 accO[16];
#pragma unroll
    for (int i = 0; i < 16; ++i) accO[i] = fzero;
    float mrow[4], lpart[4];  // lpart: per-LANE partials, reduced in epilogue
#pragma unroll
    for (int r = 0; r < 4; ++r) {
        mrow[r] = -1e30f;
        lpart[r] = 0.f;
    }
    const int growb = r0 + w * 16 + quad * 4;
    f16* Pw = &Plds[w][0];

    // stage tile `t` into buffer `b` (each of 8 waves: 4 K-instrs + 4 V-instrs)
    auto stage = [&](int t, int b) {
        const int j0 = col0 + t * BC;
#pragma unroll
        for (int i = 0; i < 4; ++i) {
            const int r = w * 8 + i * 2 + (lane >> 5);
            gl2lds16(Kh + (size_t)(j0 + r) * DD + (((lane & 31) ^ (r & 7)) * 8),
                     &Klds[b][(w * 8 + i * 2) * 256]);
        }
#pragma unroll
        for (int i = 0; i < 4; ++i) {
            const int n = w * 32 + i * 8 + (lane >> 3);
            gl2lds16(Vt + (size_t)n * NN + j0 + (((lane & 7) ^ (n & 7)) * 8),
                     &Vlds[b][(w * 32 + i * 8) * 64]);
        }
    };

    // prologue: stage tile 0 -> buf 0
    stage(0, 0);
    __syncthreads();

#pragma unroll 1
    for (int it = 0; it < NIT; ++it) {
        const int cur = it & 1;
        const int j0 = col0 + it * BC;

        // stage NEXT tile into alternate buffer (covered by this iter's compute)
        if (it + 1 < NIT) stage(it + 1, cur ^ 1);

        // adjacency for this tile (nontemporal: streamed once)
        int av[4][4];
#pragma unroll
        for (int rgi = 0; rgi < 4; ++rgi)
#pragma unroll
            for (int jt = 0; jt < 4; ++jt)
                av[rgi][jt] = __builtin_nontemporal_load(
                    A + (size_t)(growb + rgi) * NN + j0 + jt * 16 + l15);

        // S = (Qh+Ql)·Kh^T : both 32-col halves issued back-to-back so the
        // h1 MFMAs drain under SM(h0)'s VALU
        f32x4 accS[4];
#pragma unroll
        for (int jt = 0; jt < 4; ++jt) accS[jt] = fzero;
        __builtin_amdgcn_s_setprio(1);
#pragma unroll
        for (int kc = 0; kc < 8; ++kc)
#pragma unroll
            for (int jt = 0; jt < 2; ++jt) {
                const int r = jt * 16 + l15;
                const f16x8 kf =
                    *(const f16x8*)&Klds[cur][r * 256 + (((kc * 4 + quad) ^ (r & 7)) * 8)];
                accS[jt] = MFMA(qh[kc], kf, accS[jt]);
                accS[jt] = MFMA(ql[kc], kf, accS[jt]);
            }
#pragma unroll
        for (int kc = 0; kc < 8; ++kc)
#pragma unroll
            for (int jt = 2; jt < 4; ++jt) {
                const int r = jt * 16 + l15;
                const f16x8 kf =
                    *(const f16x8*)&Klds[cur][r * 256 + (((kc * 4 + quad) ^ (r & 7)) * 8)];
                accS[jt] = MFMA(qh[kc], kf, accS[jt]);
                accS[jt] = MFMA(ql[kc], kf, accS[jt]);
            }
        __builtin_amdgcn_s_setprio(0);

        // ---- two online-softmax sub-tiles: SM(h), PV(h) for h = 0,1 ----
#pragma unroll
        for (int h = 0; h < 2; ++h) {
            // SM(h): mask, 32-col row max, exact defer-rescale, exp, P write
#pragma unroll
            for (int rgi = 0; rgi < 4; ++rgi) {
                const int gr = growb + rgi;
                float mx = -3.0e38f;
#pragma unroll
                for (int jt = 2 * h; jt < 2 * h + 2; ++jt) {
                    const int gc = j0 + jt * 16 + l15;
                    const float s =
                        (av[rgi][jt] != 0 || gr == gc) ? accS[jt][rgi] : -3.0e38f;
                    accS[jt][rgi] = s;
                    mx = fmaxf(mx, s);
                }
#pragma unroll
                for (int off = 1; off < 16; off <<= 1)
                    mx = fmaxf(mx, __shfl_xor(mx, off, 64));
                const float mnew = fmaxf(mrow[rgi], mx);
                if (__any(mnew > mrow[rgi])) {
                    const float al = __expf(mrow[rgi] - mnew);
                    mrow[rgi] = mnew;
                    lpart[rgi] *= al;
#pragma unroll
                    for (int nt = 0; nt < 16; ++nt) accO[nt][rgi] *= al;
                }
                float rs = 0.f;
                const int row = quad * 4 + rgi;
#pragma unroll
                for (int jt = 2 * h; jt < 2 * h + 2; ++jt) {
                    const float s = accS[jt][rgi];
                    const float e = (s > -1.0e37f) ? __expf(s - mrow[rgi]) : 0.f;
                    rs += e;
                    Pw[row * PSTR + ((jt * 16 + l15) ^ ((row & 7) << 3))] = (f16)e;
                }
                lpart[rgi] += rs;  // per-lane; epilogue reduce
            }

            // P A-frag for this half (in-order LDS pipe, no barrier)
            const f16x8 pf =
                *(const f16x8*)&Pw[l15 * PSTR + ((h * 32 + quad * 8) ^ ((l15 & 7) << 3))];

            // PV(h): 16 rows x 256 n, k-half h
            __builtin_amdgcn_s_setprio(1);
#pragma unroll
            for (int nt = 0; nt < 16; ++nt) {
                const int n = nt * 16 + l15;
                const f16x8 vf =
                    *(const f16x8*)&Vlds[cur][n * 64 + (((h * 4 + quad) ^ (n & 7)) * 8)];
                accO[nt] = MFMA(pf, vf, accO[nt]);
            }
            __builtin_amdgcn_s_setprio(0);
        }

        // single barrier: compute(it) done before buf overwrite; drains stage(it+1)
        __syncthreads();
    }

    // epilogue: reduce per-lane l partials across 16 lanes (once)
#pragma unroll
    for (int rgi = 0; rgi < 4; ++rgi)
#pragma unroll
        for (int off = 1; off < 16; off <<= 1)
            lpart[rgi] += __shfl_xor(lpart[rgi], off, 64);

    // write partials
#pragma unroll
    for (int nt = 0; nt < 16; ++nt)
#pragma unroll
        for (int rgi = 0; rgi < 4; ++rgi)
            pO[((size_t)cch * NN + growb + rgi) * DD + nt * 16 + l15] = accO[nt][rgi];
    if (l15 == 0) {
#pragma unroll
        for (int rgi = 0; rgi < 4; ++rgi) {
            pM[(size_t)cch * NN + growb + rgi] = mrow[rgi];
            pL[(size_t)cch * NN + growb + rgi] = lpart[rgi];
        }
    }
}

// ---------------- merge partials (8 rows/block) ----------------
__global__ __launch_bounds__(256) void merge_kernel(const float* __restrict__ pO,
                                                    const float* __restrict__ pM,
                                                    const float* __restrict__ pL,
                                                    float* __restrict__ out) {
    const int n = threadIdx.x;
#pragma unroll 1
    for (int rr = 0; rr < 8; ++rr) {
        const int row = blockIdx.x * 8 + rr;
        float mc[CCH], lc[CCH];
        float M = -3e38f;
#pragma unroll
        for (int c = 0; c < CCH; ++c) {
            mc[c] = pM[(size_t)c * NN + row];
            lc[c] = pL[(size_t)c * NN + row];
            M = fmaxf(M, mc[c]);
        }
        float L = 0.f, acc = 0.f;
#pragma unroll
        for (int c = 0; c < CCH; ++c) {
            const float wgt = __expf(mc[c] - M);
            L += wgt * lc[c];
            acc += wgt * pO[((size_t)c * NN + row) * DD + n];
        }
        out[(size_t)row * DD + n] = acc / L;
    }
}

extern "C" void kernel_launch(void* const* d_in, const int* in_sizes, int n_in,
                              void* d_out, int out_size, void* d_ws, size_t ws_size,
                              hipStream_t stream) {
    const float* X = (const float*)d_in[0];
    const int* A = (const int*)d_in[1];
    const float* Wq = (const float*)d_in[2];
    const float* Wk = (const float*)d_in[3];
    const float* Wv = (const float*)d_in[4];
    float* out = (float*)d_out;

    char* ws = (char*)d_ws;
    const size_t MB = 1ull << 20;
    f16* Xh = (f16*)(ws + 0 * MB);
    f16* Xl = (f16*)(ws + 4 * MB);
    f16* WtH = (f16*)(ws + 8 * MB);
    f16* WtL = (f16*)(ws + 8 * MB + 512 * 1024);
    f16* Qh = (f16*)(ws + 9 * MB);
    f16* Ql = (f16*)(ws + 13 * MB);
    f16* Kh = (f16*)(ws + 17 * MB);
    f16* Vt = (f16*)(ws + 21 * MB);
    float* pO = (float*)(ws + 25 * MB);
    float* pM = (float*)(ws + 57 * MB);
    float* pL = (float*)(ws + 57 * MB + 256 * 1024);
    (void)ws_size; (void)in_sizes; (void)n_in; (void)out_size;

    splitX_kernel<<<2048, 256, 0, stream>>>((const float4*)X, (f16x4*)Xh, (f16x4*)Xl);
    splitW_kernel<<<768, 256, 0, stream>>>(Wq, Wk, Wv, WtH, WtL);
    qkv_kernel<<<dim3(NN / 64, 3), 256, 0, stream>>>(Xh, Xl, WtH, WtL, Qh, Ql, Kh, Vt);
    flash_kernel<<<(NN / BR) * CCH, 512, 0, stream>>>(Qh, Ql, Kh, Vt, A, pO, pM, pL);
    merge_kernel<<<NN / 8, 256, 0, stream>>>(pO, pM, pL, out);
}

// Round 4
// 494.916 us; speedup vs baseline: 1.5355x; 1.0448x over previous
//
#include <hip/hip_runtime.h>
#include <stdint.h>

// GATConv fused v14 = v11 (proven 183us flash) + two LDS-pipe reliefs.
// R2 lesson: per-wave state ~188 regs (124V+64A) -> 2 waves/SIMD is a hard
// floor; occupancy is a dead end in this structure. R3 lesson: h-splitting
// the tile adds serial softmax work, no overlap. LDS pipe is ~62% of the
// tile budget (512 b128 x 12cy + conflicts + 128 bpermute shfls per CU-tile)
// and K/V read count is decomposition-invariant -> relieve at instr level:
//  (1) __shfl_xor -> DPP (mov_dpp quad_perm/mirror + v_max): shfl lowers to
//      ds_bpermute (LDS pipe!). 16 bpermutes/wave/tile move to the VALU pipe
//      and the 4-deep serial chain shortens. Same for epilogue l-sum.
//  (2) PSTR 80->68 f16 (136B row stride), XOR dropped: 4*136 = 544 = 32
//      (mod 128) -> quad write phases {0,32,64,96}, all distinct; 64 lanes
//      cover all 32 banks at the b16 2-lane/dword floor. v11's XOR at stride
//      160 only split quads into 2 classes (why conflicts stalled at 8.9M).

typedef _Float16 f16;
typedef unsigned short u16;
typedef __attribute__((ext_vector_type(8))) _Float16 f16x8;
typedef __attribute__((ext_vector_type(4))) _Float16 f16x4;
typedef __attribute__((ext_vector_type(4))) float f32x4;

#define NN 8192
#define DD 256
#define BR 128
#define BC 64
#define CCH 4
#define COLS (NN / CCH)  // 2048
#define NIT (COLS / BC)  // 32
#define PSTR 68          // P row stride in f16 (136 B: quad phases 0/32/64/96)

#define MFMA(a, b, c) __builtin_amdgcn_mfma_f32_16x16x32_f16((a), (b), (c), 0, 0, 0)

__device__ __forceinline__ void gl2lds16(const void* g, void* l) {
    __builtin_amdgcn_global_load_lds(
        (const __attribute__((address_space(1))) unsigned int*)g,
        (__attribute__((address_space(3))) unsigned int*)l, 16, 0, 0);
}

__device__ __forceinline__ u16 f16bits(f16 h) {
    union { f16 h; u16 u; } c;
    c.h = h;
    return c.u;
}

// 16-lane butterfly reduce on the VALU pipe (DPP), replacing ds_bpermute
// shfls. Steps: quad_perm[1,0,3,2]=xor1, quad_perm[2,3,0,1]=xor2,
// row_half_mirror (merges quads within 8), row_mirror (merges 8-halves).
// Valid because after step k each 2^k group is uniform. All lanes active.
__device__ __forceinline__ float dpp_max16(float x) {
    union { float f; int i; } a, b;
    a.f = x;
    b.i = __builtin_amdgcn_mov_dpp(a.i, 0xB1, 0xf, 0xf, true);
    a.f = fmaxf(a.f, b.f);
    b.i = __builtin_amdgcn_mov_dpp(a.i, 0x4E, 0xf, 0xf, true);
    a.f = fmaxf(a.f, b.f);
    b.i = __builtin_amdgcn_mov_dpp(a.i, 0x141, 0xf, 0xf, true);
    a.f = fmaxf(a.f, b.f);
    b.i = __builtin_amdgcn_mov_dpp(a.i, 0x140, 0xf, 0xf, true);
    a.f = fmaxf(a.f, b.f);
    return a.f;
}

__device__ __forceinline__ float dpp_sum16(float x) {
    union { float f; int i; } a, b;
    a.f = x;
    b.i = __builtin_amdgcn_mov_dpp(a.i, 0xB1, 0xf, 0xf, true);
    a.f += b.f;
    b.i = __builtin_amdgcn_mov_dpp(a.i, 0x4E, 0xf, 0xf, true);
    a.f += b.f;
    b.i = __builtin_amdgcn_mov_dpp(a.i, 0x141, 0xf, 0xf, true);
    a.f += b.f;
    b.i = __builtin_amdgcn_mov_dpp(a.i, 0x140, 0xf, 0xf, true);
    a.f += b.f;
    return a.f;
}

// ---------------- split X to fp16 hi/lo (4 elems/thread) ----------------
__global__ void splitX_kernel(const float4* __restrict__ X, f16x4* __restrict__ Xh,
                              f16x4* __restrict__ Xl) {
    const int i = blockIdx.x * blockDim.x + threadIdx.x;  // 524288
    const float4 v = X[i];
    const f16 h0 = (f16)v.x, h1 = (f16)v.y, h2 = (f16)v.z, h3 = (f16)v.w;
    f16x4 H = {h0, h1, h2, h3};
    f16x4 L = {(f16)(v.x - (float)h0), (f16)(v.y - (float)h1), (f16)(v.z - (float)h2),
               (f16)(v.w - (float)h3)};
    Xh[i] = H;
    Xl[i] = L;
}

// W[k][n] (3 mats 256x256) -> Wt[(mat*256+n)][k] fp16 hi/lo (transposed)
__global__ void splitW_kernel(const float* __restrict__ Wq, const float* __restrict__ Wk,
                              const float* __restrict__ Wv, f16* __restrict__ WtH,
                              f16* __restrict__ WtL) {
    const int i = blockIdx.x * blockDim.x + threadIdx.x;  // 3*65536
    const int mat = i >> 16;
    const int k = (i >> 8) & 255;
    const int n = i & 255;
    const float* W = (mat == 0) ? Wq : ((mat == 1) ? Wk : Wv);
    const float v = W[k * 256 + n];
    const f16 h = (f16)v;
    const size_t o = (size_t)(mat * 256 + n) * 256 + k;
    WtH[o] = h;
    WtL[o] = (f16)(v - (float)h);
}

// ---------------- QKV GEMM: LDS-staged W chunks, X frags in registers ----------------
__global__ __launch_bounds__(256, 2) void qkv_kernel(
    const f16* __restrict__ Xh, const f16* __restrict__ Xl,
    const f16* __restrict__ WtH, const f16* __restrict__ WtL,
    f16* __restrict__ Qh, f16* __restrict__ Ql,
    f16* __restrict__ Kh, f16* __restrict__ Vt) {
    __shared__ f16 Wh[64 * 256];
    __shared__ f16 Wl[64 * 256];
    const int lane = threadIdx.x & 63;
    const int w = threadIdx.x >> 6;
    const int l15 = lane & 15;
    const int quad = lane >> 4;
    const int r0 = blockIdx.x * 64;
    const int mat = blockIdx.y;

    f16x8 xh[8], xl[8];
    const size_t xb = (size_t)(r0 + w * 16 + l15) * DD + quad * 8;
#pragma unroll
    for (int kc = 0; kc < 8; ++kc) {
        xh[kc] = *(const f16x8*)(Xh + xb + kc * 32);
        xl[kc] = *(const f16x8*)(Xl + xb + kc * 32);
    }
    const int orow = r0 + w * 16 + quad * 4;

#pragma unroll 1
    for (int c = 0; c < 4; ++c) {
        const int nb = mat * 256 + c * 64;
#pragma unroll
        for (int i = 0; i < 8; ++i) {
            const int r = w * 16 + i * 2 + (lane >> 5);
            gl2lds16(WtH + (size_t)(nb + r) * DD + (((lane & 31) ^ (r & 7)) * 8),
                     &Wh[(w * 16 + i * 2) * 256]);
        }
#pragma unroll
        for (int i = 0; i < 8; ++i) {
            const int r = w * 16 + i * 2 + (lane >> 5);
            gl2lds16(WtL + (size_t)(nb + r) * DD + (((lane & 31) ^ (r & 7)) * 8),
                     &Wl[(w * 16 + i * 2) * 256]);
        }
        __syncthreads();

        const f32x4 fzero = {0.f, 0.f, 0.f, 0.f};
        f32x4 acc[4];
#pragma unroll
        for (int nt = 0; nt < 4; ++nt) acc[nt] = fzero;
#pragma unroll
        for (int kc = 0; kc < 8; ++kc)
#pragma unroll
            for (int nt = 0; nt < 4; ++nt) {
                const int r = nt * 16 + l15;
                const int blk = (((kc * 4 + quad) ^ (r & 7)) * 8);
                const f16x8 wh = *(const f16x8*)&Wh[r * 256 + blk];
                const f16x8 wl = *(const f16x8*)&Wl[r * 256 + blk];
                acc[nt] = MFMA(xh[kc], wh, acc[nt]);
                acc[nt] = MFMA(xh[kc], wl, acc[nt]);
                acc[nt] = MFMA(xl[kc], wh, acc[nt]);
            }

        if (mat == 0) {
#pragma unroll
            for (int nt = 0; nt < 4; ++nt)
#pragma unroll
                for (int rg = 0; rg < 4; ++rg) {
                    const int col = c * 64 + nt * 16 + l15;
                    const float v = acc[nt][rg];
                    const f16 h = (f16)v;
                    Qh[(size_t)(orow + rg) * DD + col] = h;
                    Ql[(size_t)(orow + rg) * DD + col] = (f16)(v - (float)h);
                }
        } else if (mat == 1) {
#pragma unroll
            for (int nt = 0; nt < 4; ++nt)
#pragma unroll
                for (int rg = 0; rg < 4; ++rg) {
                    const int col = c * 64 + nt * 16 + l15;
                    Kh[(size_t)(orow + rg) * DD + col] = (f16)acc[nt][rg];
                }
        } else {
#pragma unroll
            for (int nt = 0; nt < 4; ++nt) {
                const int n = c * 64 + nt * 16 + l15;
                ushort4 pk;
                pk.x = f16bits((f16)acc[nt][0]);
                pk.y = f16bits((f16)acc[nt][1]);
                pk.z = f16bits((f16)acc[nt][2]);
                pk.w = f16bits((f16)acc[nt][3]);
                *(ushort4*)(Vt + (size_t)n * NN + orow) = pk;
            }
        }
        __syncthreads();
    }
}

// ---------------- flash kernel v14 (v11 + DPP reduce + PSTR 68 no-XOR) ----------
// grid 256 linear: cch = bid&3 (pins chunk to XCD pair), rowblk = bid>>2, BR=128.
__global__ __launch_bounds__(512, 2) void flash_kernel(
    const f16* __restrict__ Qh, const f16* __restrict__ Ql,
    const f16* __restrict__ Kh, const f16* __restrict__ Vt,
    const int* __restrict__ A,
    float* __restrict__ pO, float* __restrict__ pM, float* __restrict__ pL) {
    __shared__ f16 Klds[2][64 * 256];   // 64 KB dbuf, [j][k] XOR-swizzled by j&7
    __shared__ f16 Vlds[2][256 * 64];   // 64 KB dbuf, [n][j] swizzled by n&7
    __shared__ f16 Plds[8][16 * PSTR];  // 17 KB, per-wave, stride 68 (bank-clean)

    const int lane = threadIdx.x & 63;
    const int w = threadIdx.x >> 6;  // 0..7
    const int l15 = lane & 15;
    const int quad = lane >> 4;
    const int bid = blockIdx.x;
    const int cch = bid & 3;
    const int r0 = (bid >> 2) * BR;
    const int col0 = cch * COLS;

    // Q fragments resident (A-layout m=l15, k=quad*8+i), hi+lo
    f16x8 qh[8], ql[8];
    {
        const size_t qb = (size_t)(r0 + w * 16 + l15) * DD + quad * 8;
#pragma unroll
        for (int kc = 0; kc < 8; ++kc) {
            qh[kc] = *(const f16x8*)(Qh + qb + kc * 32);
            ql[kc] = *(const f16x8*)(Ql + qb + kc * 32);
        }
    }

    const f32x4 fzero = {0.f, 0.f, 0.f, 0.f};
    f32x4 accO[16];
#pragma unroll
    for (int i = 0; i < 16; ++i) accO[i] = fzero;
    float mrow[4], lpart[4];  // lpart: per-LANE partials, reduced in epilogue
#pragma unroll
    for (int r = 0; r < 4; ++r) {
        mrow[r] = -1e30f;
        lpart[r] = 0.f;
    }
    const int growb = r0 + w * 16 + quad * 4;
    f16* Pw = &Plds[w][0];

    // stage tile `t` into buffer `b` (each of 8 waves: 4 K-instrs + 4 V-instrs)
    auto stage = [&](int t, int b) {
        const int j0 = col0 + t * BC;
#pragma unroll
        for (int i = 0; i < 4; ++i) {
            const int r = w * 8 + i * 2 + (lane >> 5);
            gl2lds16(Kh + (size_t)(j0 + r) * DD + (((lane & 31) ^ (r & 7)) * 8),
                     &Klds[b][(w * 8 + i * 2) * 256]);
        }
#pragma unroll
        for (int i = 0; i < 4; ++i) {
            const int n = w * 32 + i * 8 + (lane >> 3);
            gl2lds16(Vt + (size_t)n * NN + j0 + (((lane & 7) ^ (n & 7)) * 8),
                     &Vlds[b][(w * 32 + i * 8) * 64]);
        }
    };

    // prologue: stage tile 0 -> buf 0
    stage(0, 0);
    __syncthreads();

#pragma unroll 1
    for (int it = 0; it < NIT; ++it) {
        const int cur = it & 1;
        const int j0 = col0 + it * BC;

        // stage NEXT tile into alternate buffer (covered by this iter's compute)
        if (it + 1 < NIT) stage(it + 1, cur ^ 1);

        // adjacency for this tile (nontemporal: streamed once)
        int av[4][4];
#pragma unroll
        for (int rgi = 0; rgi < 4; ++rgi)
#pragma unroll
            for (int jt = 0; jt < 4; ++jt)
                av[rgi][jt] = __builtin_nontemporal_load(
                    A + (size_t)(growb + rgi) * NN + j0 + jt * 16 + l15);

        // S = (Qh+Ql)·Kh^T : 16 rows x 64 cols per wave
        f32x4 accS[4];
#pragma unroll
        for (int jt = 0; jt < 4; ++jt) accS[jt] = fzero;
        __builtin_amdgcn_s_setprio(1);
#pragma unroll
        for (int kc = 0; kc < 8; ++kc)
#pragma unroll
            for (int jt = 0; jt < 4; ++jt) {
                const int r = jt * 16 + l15;
                const f16x8 kf =
                    *(const f16x8*)&Klds[cur][r * 256 + (((kc * 4 + quad) ^ (r & 7)) * 8)];
                accS[jt] = MFMA(qh[kc], kf, accS[jt]);
                accS[jt] = MFMA(ql[kc], kf, accS[jt]);
            }
        __builtin_amdgcn_s_setprio(0);

        // wave-local online softmax (DPP max reduce -- VALU pipe, not LDS;
        // exact defer-rescale: alpha==1 path skipped, bitwise-identical)
#pragma unroll
        for (int rgi = 0; rgi < 4; ++rgi) {
            const int gr = growb + rgi;
            float mx = -3.0e38f;
#pragma unroll
            for (int jt = 0; jt < 4; ++jt) {
                const int gc = j0 + jt * 16 + l15;
                const float s = (av[rgi][jt] != 0 || gr == gc) ? accS[jt][rgi] : -3.0e38f;
                accS[jt][rgi] = s;
                mx = fmaxf(mx, s);
            }
            mx = dpp_max16(mx);
            const float mnew = fmaxf(mrow[rgi], mx);
            if (__any(mnew > mrow[rgi])) {
                const float al = __expf(mrow[rgi] - mnew);
                mrow[rgi] = mnew;
                lpart[rgi] *= al;
#pragma unroll
                for (int nt = 0; nt < 16; ++nt) accO[nt][rgi] *= al;
            }
            float rs = 0.f;
            const int row = quad * 4 + rgi;
#pragma unroll
            for (int jt = 0; jt < 4; ++jt) {
                const float s = accS[jt][rgi];
                const float e = (s > -1.0e37f) ? __expf(s - mrow[rgi]) : 0.f;
                rs += e;
                Pw[row * PSTR + jt * 16 + l15] = (f16)e;
            }
            lpart[rgi] += rs;  // per-lane; epilogue reduce
        }

        // P A-frags (per-wave LDS round trip; in-order LDS pipe, no barrier)
        f16x8 pf[2];
        pf[0] = *(const f16x8*)&Pw[l15 * PSTR + quad * 8];
        pf[1] = *(const f16x8*)&Pw[l15 * PSTR + 32 + quad * 8];

        // PV: 16 rows x 256 n per wave
        __builtin_amdgcn_s_setprio(1);
#pragma unroll
        for (int nt = 0; nt < 16; ++nt)
#pragma unroll
            for (int kc2 = 0; kc2 < 2; ++kc2) {
                const int n = nt * 16 + l15;
                const f16x8 vf =
                    *(const f16x8*)&Vlds[cur][n * 64 + (((kc2 * 4 + quad) ^ (n & 7)) * 8)];
                accO[nt] = MFMA(pf[kc2], vf, accO[nt]);
            }
        __builtin_amdgcn_s_setprio(0);

        // single barrier: compute(it) done before buf overwrite; drains stage(it+1)
        __syncthreads();
    }

    // epilogue: reduce per-lane l partials across 16 lanes (DPP, once)
#pragma unroll
    for (int rgi = 0; rgi < 4; ++rgi) lpart[rgi] = dpp_sum16(lpart[rgi]);

    // write partials
#pragma unroll
    for (int nt = 0; nt < 16; ++nt)
#pragma unroll
        for (int rgi = 0; rgi < 4; ++rgi)
            pO[((size_t)cch * NN + growb + rgi) * DD + nt * 16 + l15] = accO[nt][rgi];
    if (l15 == 0) {
#pragma unroll
        for (int rgi = 0; rgi < 4; ++rgi) {
            pM[(size_t)cch * NN + growb + rgi] = mrow[rgi];
            pL[(size_t)cch * NN + growb + rgi] = lpart[rgi];
        }
    }
}

// ---------------- merge partials (8 rows/block) ----------------
__global__ __launch_bounds__(256) void merge_kernel(const float* __restrict__ pO,
                                                    const float* __restrict__ pM,
                                                    const float* __restrict__ pL,
                                                    float* __restrict__ out) {
    const int n = threadIdx.x;
#pragma unroll 1
    for (int rr = 0; rr < 8; ++rr) {
        const int row = blockIdx.x * 8 + rr;
        float mc[CCH], lc[CCH];
        float M = -3e38f;
#pragma unroll
        for (int c = 0; c < CCH; ++c) {
            mc[c] = pM[(size_t)c * NN + row];
            lc[c] = pL[(size_t)c * NN + row];
            M = fmaxf(M, mc[c]);
        }
        float L = 0.f, acc = 0.f;
#pragma unroll
        for (int c = 0; c < CCH; ++c) {
            const float wgt = __expf(mc[c] - M);
            L += wgt * lc[c];
            acc += wgt * pO[((size_t)c * NN + row) * DD + n];
        }
        out[(size_t)row * DD + n] = acc / L;
    }
}

extern "C" void kernel_launch(void* const* d_in, const int* in_sizes, int n_in,
                              void* d_out, int out_size, void* d_ws, size_t ws_size,
                              hipStream_t stream) {
    const float* X = (const float*)d_in[0];
    const int* A = (const int*)d_in[1];
    const float* Wq = (const float*)d_in[2];
    const float* Wk = (const float*)d_in[3];
    const float* Wv = (const float*)d_in[4];
    float* out = (float*)d_out;

    char* ws = (char*)d_ws;
    const size_t MB = 1ull << 20;
    f16* Xh = (f16*)(ws + 0 * MB);
    f16* Xl = (f16*)(ws + 4 * MB);
    f16* WtH = (f16*)(ws + 8 * MB);
    f16* WtL = (f16*)(ws + 8 * MB + 512 * 1024);
    f16* Qh = (f16*)(ws + 9 * MB);
    f16* Ql = (f16*)(ws + 13 * MB);
    f16* Kh = (f16*)(ws + 17 * MB);
    f16* Vt = (f16*)(ws + 21 * MB);
    float* pO = (float*)(ws + 25 * MB);
    float* pM = (float*)(ws + 57 * MB);
    float* pL = (float*)(ws + 57 * MB + 256 * 1024);
    (void)ws_size; (void)in_sizes; (void)n_in; (void)out_size;

    splitX_kernel<<<2048, 256, 0, stream>>>((const float4*)X, (f16x4*)Xh, (f16x4*)Xl);
    splitW_kernel<<<768, 256, 0, stream>>>(Wq, Wk, Wv, WtH, WtL);
    qkv_kernel<<<dim3(NN / 64, 3), 256, 0, stream>>>(Xh, Xl, WtH, WtL, Qh, Ql, Kh, Vt);
    flash_kernel<<<(NN / BR) * CCH, 512, 0, stream>>>(Qh, Ql, Kh, Vt, A, pO, pM, pL);
    merge_kernel<<<NN / 8, 256, 0, stream>>>(pO, pM, pL, out);
}